// Round 2
// baseline (294.293 us; speedup 1.0000x reference)
//
#include <hip/hip_runtime.h>
#include <stdint.h>

using f32x4   = __attribute__((ext_vector_type(4))) float;
using short8  = __attribute__((ext_vector_type(8))) short;
using float4v = __attribute__((ext_vector_type(4))) float;
using float2v = __attribute__((ext_vector_type(2))) float;
using uint2v  = __attribute__((ext_vector_type(2))) unsigned int;
using uint4v  = __attribute__((ext_vector_type(4))) unsigned int;

#define NCOL 11008
#define KDIM 4096
#define BSTRIDE 72    // LDS bytes per k-row: 32 cols * 2B + 8B pad

__device__ __forceinline__ unsigned pk_bf16(float a, float b) {
  unsigned ua = __float_as_uint(a); ua += 0x7fffu + ((ua >> 16) & 1u);  // RNE
  unsigned ub = __float_as_uint(b); ub += 0x7fffu + ((ub >> 16) & 1u);
  return (ua >> 16) | (ub & 0xffff0000u);
}

// ---- kernel 1: mask (fp64-exact; verified green) + write mask-zeroed bf16
//      copy of x into ws. grid (8 rb, 8 kgrp), 256 thr. UNCHANGED.
__global__ __launch_bounds__(256) void mask_convert_kernel(
    const float* __restrict__ x, unsigned* __restrict__ xbf) {
  const int rb = blockIdx.x;
  const int g  = blockIdx.y;
  const int t  = threadIdx.x;
  __shared__ double part[256];
  __shared__ unsigned sh_bits;

  const float* base = x + (size_t)rb * 16 * KDIM + g * 512 + t * 2;
  double s = 0.0;
#pragma unroll
  for (int r = 0; r < 16; ++r) {
    float2v a = *(const float2v*)(base + (size_t)r * KDIM);
    s += (double)fabsf(a[0]) + (double)fabsf(a[1]);
  }
  part[t] = s;
  __syncthreads();
  if (t < 8) {                        // t = kb-local (8 kbs per 512-col group)
    double acc = 0.0;
#pragma unroll
    for (int u = 0; u < 32; ++u) acc += part[t * 32 + u];
    bool on = (acc * (1.0 / 1024.0)) > (double)0.8f;
    unsigned long long bal = __ballot(on);
    if (t == 0) sh_bits = (unsigned)(bal & 0xffu);
  }
  __syncthreads();
  const unsigned keep = (sh_bits >> (t >> 5)) & 1u;

  unsigned* dst = xbf + (size_t)rb * 16 * (KDIM / 2) + g * 256 + t;
#pragma unroll
  for (int r = 0; r < 16; ++r) {      // reload (L1-hot) + pack/zero + store
    float2v a = *(const float2v*)(base + (size_t)r * KDIM);
    dst[(size_t)r * (KDIM / 2)] = keep ? pk_bf16(a[0], a[1]) : 0u;
  }
}

// ---- kernel 2: dense GEMM on masked bf16 x. grid 344, 256 thr (4 waves).
// M=128 x N=32 per block, full K. LDS double-buffered W tile.
// NEW this round (T4): __syncthreads() replaced by raw s_barrier + explicit
// lgkmcnt(0). __syncthreads forced s_waitcnt vmcnt(0) every phase, draining
// the W/A prefetch queue (the R1 no-op). With the raw barrier the compiler
// emits COUNTED vmcnt waits at first use (W[k] = oldest 2 of 12 -> vmcnt(10),
// A[k] -> vmcnt(8)), keeping W[k+1],A[k+1],W[k+2] in flight across barriers.
// Depth-2 for BOTH W and A; A issued after its consumer frees the regs.
__global__ __launch_bounds__(256) void gemm_kernel(
    const unsigned* __restrict__ xbf, const float* __restrict__ w,
    const float* __restrict__ bias, float* __restrict__ out) {

  __shared__ __align__(16) uint8_t lds[2 * 64 * BSTRIDE];

  const int tid  = threadIdx.x;
  const int lane = tid & 63;
  const int wv   = tid >> 6;
  const int c    = lane & 15;
  const int q    = lane >> 4;
  const int n0   = blockIdx.x * 32;

  f32x4 acc[2][2] = {};               // [band][even/odd]

  // W staging: thread t -> rows {t>>3, (t>>3)+32}, col chunk (t&7)*4
  const int sk = tid >> 3;            // 0..31
  const int sn = (tid & 7) * 4;       // 0,4,..,28
  const size_t wOff = (size_t)sk * NCOL + n0 + sn;

  auto issueW = [&](int kbi, float4v& r0, float4v& r1) {
    const float* wp = w + (size_t)kbi * 64 * NCOL + wOff;
    r0 = *(const float4v*)(wp);
    r1 = *(const float4v*)(wp + (size_t)32 * NCOL);
  };
  auto storeW = [&](uint8_t* buf, const float4v& r0, const float4v& r1) {
    uint2v v;
    v[0] = pk_bf16(r0[0], r0[1]);
    v[1] = pk_bf16(r0[2], r0[3]);
    *(uint2v*)(buf + (size_t)sk * BSTRIDE + sn * 2) = v;
    uint2v u;
    u[0] = pk_bf16(r1[0], r1[1]);
    u[1] = pk_bf16(r1[2], r1[3]);
    *(uint2v*)(buf + (size_t)(sk + 32) * BSTRIDE + sn * 2) = u;
  };

  // A source (bf16 masked x, L2-resident): uint4v idx = row*512 + kb*8 + ks*4 + q
  const uint4v* aB0 = (const uint4v*)xbf + (size_t)((wv * 2 + 0) * 16 + c) * (KDIM / 8) + q;
  const uint4v* aB1 = (const uint4v*)xbf + (size_t)((wv * 2 + 1) * 16 + c) * (KDIM / 8) + q;

  auto loadA = [&](int kbi, uint4v* AR) {
    AR[0] = aB0[kbi * 8 + 0];   // band0 ks=0
    AR[1] = aB0[kbi * 8 + 4];   // band0 ks=1
    AR[2] = aB1[kbi * 8 + 0];   // band1 ks=0
    AR[3] = aB1[kbi * 8 + 4];   // band1 ks=1
  };

  auto compute = [&](const uint8_t* buf, const uint4v* AR) {
#pragma unroll
    for (int ks = 0; ks < 2; ++ks) {
      union { uint4v u; short8 v; } a0, a1;
      a0.u = AR[ks];
      a1.u = AR[2 + ks];

      // B fragments: dword j = cols (2c,2c+1) at k = ks*32 + q*8 + j
      const uint8_t* wb = buf + (size_t)(ks * 32 + q * 8) * BSTRIDE + c * 4;
      unsigned wj[8];
#pragma unroll
      for (int j = 0; j < 8; ++j)
        wj[j] = *(const unsigned*)(wb + (size_t)j * BSTRIDE);
      union { short8 v; unsigned u[4]; } be, bo;
#pragma unroll
      for (int pp = 0; pp < 4; ++pp) {
        be.u[pp] = (wj[2 * pp] & 0x0000ffffu) | (wj[2 * pp + 1] << 16);   // even
        bo.u[pp] = (wj[2 * pp] >> 16) | (wj[2 * pp + 1] & 0xffff0000u);   // odd
      }
      acc[0][0] = __builtin_amdgcn_mfma_f32_16x16x32_bf16(a0.v, be.v, acc[0][0], 0, 0, 0);
      acc[0][1] = __builtin_amdgcn_mfma_f32_16x16x32_bf16(a0.v, bo.v, acc[0][1], 0, 0, 0);
      acc[1][0] = __builtin_amdgcn_mfma_f32_16x16x32_bf16(a1.v, be.v, acc[1][0], 0, 0, 0);
      acc[1][1] = __builtin_amdgcn_mfma_f32_16x16x32_bf16(a1.v, bo.v, acc[1][1], 0, 0, 0);
    }
  };

  // raw barrier: LDS visibility only (lgkmcnt), NO vmcnt drain.
#define BAR()                                             \
  {                                                       \
    asm volatile("s_waitcnt lgkmcnt(0)" ::: "memory");    \
    __builtin_amdgcn_s_barrier();                         \
  }

  // prologue: depth-2 in flight, queue order W[0],A[0],W[1],A[1]
  uint4v aC[4], aN[4];
  float4v wa0, wa1, wb0, wb1;         // even-kb set / odd-kb set
  issueW(0, wa0, wa1);
  loadA(0, aC);
  issueW(1, wb0, wb1);
  loadA(1, aN);

  uint8_t* const bufE = lds;                  // even-kb LDS buffer
  uint8_t* const bufO = lds + 64 * BSTRIDE;   // odd-kb LDS buffer

  for (int kb = 0; kb < 62; kb += 2) {
    // ---- even phase kb ----
    storeW(bufE, wa0, wa1);           // compiler: vmcnt wait for W[kb] only
    issueW(kb + 2, wa0, wa1);
    BAR();
    compute(bufE, aC);                // compiler: vmcnt wait for A[kb] only
    loadA(kb + 2, aC);                // regs free after compute
    // ---- odd phase kb+1 ----
    storeW(bufO, wb0, wb1);
    issueW(kb + 3, wb0, wb1);
    BAR();
    compute(bufO, aN);
    loadA(kb + 3, aN);
  }
  // ---- peeled phase 62 (no new issues) ----
  storeW(bufE, wa0, wa1);
  BAR();
  compute(bufE, aC);
  // ---- peeled phase 63 ----
  storeW(bufO, wb0, wb1);
  BAR();
  compute(bufO, aN);
#undef BAR

  // epilogue: D row = band*16 + q*4 + pp, cols (2c,2c+1); direct fp32 store
  const int colE = n0 + 2 * c;
  const float bE = bias[colE];
  const float bO = bias[colE + 1];
#pragma unroll
  for (int b = 0; b < 2; ++b) {
#pragma unroll
    for (int pp = 0; pp < 4; ++pp) {
      const int row = (wv * 2 + b) * 16 + q * 4 + pp;
      float2v st;
      st[0] = acc[b][0][pp] + bE;
      st[1] = acc[b][1][pp] + bO;
      *(float2v*)(out + (size_t)row * NCOL + colE) = st;   // 8B-aligned
    }
  }
}

extern "C" void kernel_launch(void* const* d_in, const int* in_sizes, int n_in,
                              void* d_out, int out_size, void* d_ws, size_t ws_size,
                              hipStream_t stream) {
  const float* x    = (const float*)d_in[0];
  const float* w    = (const float*)d_in[1];
  const float* bias = (const float*)d_in[2];
  float* out        = (float*)d_out;
  unsigned* xbf     = (unsigned*)d_ws;    // 128 x 4096 bf16 (1 MiB)

  hipLaunchKernelGGL(mask_convert_kernel, dim3(8, 8), dim3(256), 0, stream, x, xbf);
  hipLaunchKernelGGL(gemm_kernel, dim3(344), dim3(256), 0, stream,
                     xbf, w, bias, out);
}

// Round 3
// 289.922 us; speedup vs baseline: 1.0151x; 1.0151x over previous
//
#include <hip/hip_runtime.h>
#include <stdint.h>

using f32x4   = __attribute__((ext_vector_type(4))) float;
using short8  = __attribute__((ext_vector_type(8))) short;
using float4v = __attribute__((ext_vector_type(4))) float;
using float2v = __attribute__((ext_vector_type(2))) float;
using uint2v  = __attribute__((ext_vector_type(2))) unsigned int;
using uint4v  = __attribute__((ext_vector_type(4))) unsigned int;

#define NCOL 11008
#define KDIM 4096
#define BSTRIDE 72    // LDS bytes per k-row: 32 cols * 2B + 8B pad
#define KSEG 4        // K-split factor: 64 kbs -> 4 segments of 16
#define KB_PER_SEG 16

__device__ __forceinline__ unsigned pk_bf16(float a, float b) {
  unsigned ua = __float_as_uint(a); ua += 0x7fffu + ((ua >> 16) & 1u);  // RNE
  unsigned ub = __float_as_uint(b); ub += 0x7fffu + ((ub >> 16) & 1u);
  return (ua >> 16) | (ub & 0xffff0000u);
}

// ---- kernel 1: mask (fp64-exact; verified green) + write mask-zeroed bf16
//      copy of x into ws. grid (8 rb, 8 kgrp), 256 thr. UNCHANGED.
__global__ __launch_bounds__(256) void mask_convert_kernel(
    const float* __restrict__ x, unsigned* __restrict__ xbf) {
  const int rb = blockIdx.x;
  const int g  = blockIdx.y;
  const int t  = threadIdx.x;
  __shared__ double part[256];
  __shared__ unsigned sh_bits;

  const float* base = x + (size_t)rb * 16 * KDIM + g * 512 + t * 2;
  double s = 0.0;
#pragma unroll
  for (int r = 0; r < 16; ++r) {
    float2v a = *(const float2v*)(base + (size_t)r * KDIM);
    s += (double)fabsf(a[0]) + (double)fabsf(a[1]);
  }
  part[t] = s;
  __syncthreads();
  if (t < 8) {                        // t = kb-local (8 kbs per 512-col group)
    double acc = 0.0;
#pragma unroll
    for (int u = 0; u < 32; ++u) acc += part[t * 32 + u];
    bool on = (acc * (1.0 / 1024.0)) > (double)0.8f;
    unsigned long long bal = __ballot(on);
    if (t == 0) sh_bits = (unsigned)(bal & 0xffu);
  }
  __syncthreads();
  const unsigned keep = (sh_bits >> (t >> 5)) & 1u;

  unsigned* dst = xbf + (size_t)rb * 16 * (KDIM / 2) + g * 256 + t;
#pragma unroll
  for (int r = 0; r < 16; ++r) {      // reload (L1-hot) + pack/zero + store
    float2v a = *(const float2v*)(base + (size_t)r * KDIM);
    dst[(size_t)r * (KDIM / 2)] = keep ? pk_bf16(a[0], a[1]) : 0u;
  }
}

// ---- kernel 1b: out[r][n] = bias[n] so gemm ksegs can atomically accumulate
// order-free. grid (43, 128): 11008 = 43*256 cols, 128 rows.
__global__ __launch_bounds__(256) void bias_init_kernel(
    const float* __restrict__ bias, float* __restrict__ out) {
  const int n = blockIdx.x * 256 + threadIdx.x;
  out[(size_t)blockIdx.y * NCOL + n] = bias[n];
}

// ---- kernel 2: dense GEMM on masked bf16 x. grid (344, KSEG=4), 256 thr.
// M=128 x N=32 per block, 16 kbs of K per block. W still read EXACTLY ONCE
// chip-wide (ksegs partition K). NEW this round: K-split x4 for TLP —
// 1376 blocks ~= 5.4/CU so co-resident blocks hide each other's memory
// latency (R1/R2 ILP-only attempts were no-ops at 1.3 blocks/CU, occupancy
// 10%). Partial sums combined with native fp32 atomics; bias pre-written
// by bias_init_kernel. Depth-2 W/A reg prefetch + counted-vmcnt raw
// barriers retained.
__global__ __launch_bounds__(256) void gemm_kernel(
    const unsigned* __restrict__ xbf, const float* __restrict__ w,
    float* __restrict__ out) {

  __shared__ __align__(16) uint8_t lds[2 * 64 * BSTRIDE];

  const int tid  = threadIdx.x;
  const int lane = tid & 63;
  const int wv   = tid >> 6;
  const int c    = lane & 15;
  const int q    = lane >> 4;
  const int n0   = blockIdx.x * 32;
  const int kb0  = blockIdx.y * KB_PER_SEG;

  f32x4 acc[2][2] = {};               // [band][even/odd]

  // W staging: thread t -> rows {t>>3, (t>>3)+32}, col chunk (t&7)*4
  const int sk = tid >> 3;            // 0..31
  const int sn = (tid & 7) * 4;       // 0,4,..,28
  const size_t wOff = (size_t)sk * NCOL + n0 + sn;

  auto issueW = [&](int kbi, float4v& r0, float4v& r1) {
    const float* wp = w + (size_t)kbi * 64 * NCOL + wOff;
    r0 = *(const float4v*)(wp);
    r1 = *(const float4v*)(wp + (size_t)32 * NCOL);
  };
  auto storeW = [&](uint8_t* buf, const float4v& r0, const float4v& r1) {
    uint2v v;
    v[0] = pk_bf16(r0[0], r0[1]);
    v[1] = pk_bf16(r0[2], r0[3]);
    *(uint2v*)(buf + (size_t)sk * BSTRIDE + sn * 2) = v;
    uint2v u;
    u[0] = pk_bf16(r1[0], r1[1]);
    u[1] = pk_bf16(r1[2], r1[3]);
    *(uint2v*)(buf + (size_t)(sk + 32) * BSTRIDE + sn * 2) = u;
  };

  // A source (bf16 masked x, L2-resident): uint4v idx = row*512 + kb*8 + ks*4 + q
  const uint4v* aB0 = (const uint4v*)xbf + (size_t)((wv * 2 + 0) * 16 + c) * (KDIM / 8) + q;
  const uint4v* aB1 = (const uint4v*)xbf + (size_t)((wv * 2 + 1) * 16 + c) * (KDIM / 8) + q;

  auto loadA = [&](int kbi, uint4v* AR) {
    AR[0] = aB0[kbi * 8 + 0];   // band0 ks=0
    AR[1] = aB0[kbi * 8 + 4];   // band0 ks=1
    AR[2] = aB1[kbi * 8 + 0];   // band1 ks=0
    AR[3] = aB1[kbi * 8 + 4];   // band1 ks=1
  };

  auto compute = [&](const uint8_t* buf, const uint4v* AR) {
#pragma unroll
    for (int ks = 0; ks < 2; ++ks) {
      union { uint4v u; short8 v; } a0, a1;
      a0.u = AR[ks];
      a1.u = AR[2 + ks];

      // B fragments: dword j = cols (2c,2c+1) at k = ks*32 + q*8 + j
      const uint8_t* wb = buf + (size_t)(ks * 32 + q * 8) * BSTRIDE + c * 4;
      unsigned wj[8];
#pragma unroll
      for (int j = 0; j < 8; ++j)
        wj[j] = *(const unsigned*)(wb + (size_t)j * BSTRIDE);
      union { short8 v; unsigned u[4]; } be, bo;
#pragma unroll
      for (int pp = 0; pp < 4; ++pp) {
        be.u[pp] = (wj[2 * pp] & 0x0000ffffu) | (wj[2 * pp + 1] << 16);   // even
        bo.u[pp] = (wj[2 * pp] >> 16) | (wj[2 * pp + 1] & 0xffff0000u);   // odd
      }
      acc[0][0] = __builtin_amdgcn_mfma_f32_16x16x32_bf16(a0.v, be.v, acc[0][0], 0, 0, 0);
      acc[0][1] = __builtin_amdgcn_mfma_f32_16x16x32_bf16(a0.v, bo.v, acc[0][1], 0, 0, 0);
      acc[1][0] = __builtin_amdgcn_mfma_f32_16x16x32_bf16(a1.v, be.v, acc[1][0], 0, 0, 0);
      acc[1][1] = __builtin_amdgcn_mfma_f32_16x16x32_bf16(a1.v, bo.v, acc[1][1], 0, 0, 0);
    }
  };

  // raw barrier: LDS visibility only (lgkmcnt), NO vmcnt drain.
#define BAR()                                             \
  {                                                       \
    asm volatile("s_waitcnt lgkmcnt(0)" ::: "memory");    \
    __builtin_amdgcn_s_barrier();                         \
  }

  // prologue: depth-2 in flight, queue order W[0],A[0],W[1],A[1]
  uint4v aC[4], aN[4];
  float4v wa0, wa1, wb0, wb1;         // even-kb set / odd-kb set
  issueW(kb0 + 0, wa0, wa1);
  loadA(kb0 + 0, aC);
  issueW(kb0 + 1, wb0, wb1);
  loadA(kb0 + 1, aN);

  uint8_t* const bufE = lds;                  // even-kb LDS buffer
  uint8_t* const bufO = lds + 64 * BSTRIDE;   // odd-kb LDS buffer

  for (int kb = kb0; kb < kb0 + KB_PER_SEG - 2; kb += 2) {
    // ---- even phase kb ----
    storeW(bufE, wa0, wa1);           // vmcnt wait: W[kb] only (oldest)
    issueW(kb + 2, wa0, wa1);
    BAR();
    compute(bufE, aC);                // vmcnt wait: A[kb] only
    loadA(kb + 2, aC);                // regs free after compute
    // ---- odd phase kb+1 ----
    storeW(bufO, wb0, wb1);
    issueW(kb + 3, wb0, wb1);
    BAR();
    compute(bufO, aN);
    loadA(kb + 3, aN);
  }
  // ---- peeled phase kb0+14 (no new issues) ----
  storeW(bufE, wa0, wa1);
  BAR();
  compute(bufE, aC);
  // ---- peeled phase kb0+15 ----
  storeW(bufO, wb0, wb1);
  BAR();
  compute(bufO, aN);
#undef BAR

  // epilogue: D row = band*16 + q*4 + pp, cols (2c,2c+1); native fp32
  // atomic add (relaxed, agent scope -> global_atomic_add_f32). 4 ksegs
  // per address, lane-disjoint -> negligible contention.
  const int colE = n0 + 2 * c;
#pragma unroll
  for (int b = 0; b < 2; ++b) {
#pragma unroll
    for (int pp = 0; pp < 4; ++pp) {
      const int row = (wv * 2 + b) * 16 + q * 4 + pp;
      float* p = out + (size_t)row * NCOL + colE;
      __hip_atomic_fetch_add(p,     acc[b][0][pp], __ATOMIC_RELAXED,
                             __HIP_MEMORY_SCOPE_AGENT);
      __hip_atomic_fetch_add(p + 1, acc[b][1][pp], __ATOMIC_RELAXED,
                             __HIP_MEMORY_SCOPE_AGENT);
    }
  }
}

extern "C" void kernel_launch(void* const* d_in, const int* in_sizes, int n_in,
                              void* d_out, int out_size, void* d_ws, size_t ws_size,
                              hipStream_t stream) {
  const float* x    = (const float*)d_in[0];
  const float* w    = (const float*)d_in[1];
  const float* bias = (const float*)d_in[2];
  float* out        = (float*)d_out;
  unsigned* xbf     = (unsigned*)d_ws;    // 128 x 4096 bf16 (1 MiB)

  hipLaunchKernelGGL(mask_convert_kernel, dim3(8, 8), dim3(256), 0, stream, x, xbf);
  hipLaunchKernelGGL(bias_init_kernel, dim3(43, 128), dim3(256), 0, stream, bias, out);
  hipLaunchKernelGGL(gemm_kernel, dim3(344, KSEG), dim3(256), 0, stream,
                     xbf, w, out);
}

// Round 6
// 288.666 us; speedup vs baseline: 1.0195x; 1.0044x over previous
//
#include <hip/hip_runtime.h>
#include <stdint.h>

using f32x4   = __attribute__((ext_vector_type(4))) float;
using short8  = __attribute__((ext_vector_type(8))) short;
using float2v = __attribute__((ext_vector_type(2))) float;
using uint4v  = __attribute__((ext_vector_type(4))) unsigned int;

#define NCOL 11008
#define KDIM 4096
#define KSEG 4        // K-split factor: 64 kbs -> 4 segments of 16
#define KB_PER_SEG 16
#define TILE_B 8192   // W tile: 64 k-rows x 32 cols fp32 = 64*128 B

#define AS1 __attribute__((address_space(1)))
#define AS3 __attribute__((address_space(3)))

__device__ __forceinline__ unsigned pk_bf16(float a, float b) {
  unsigned ua = __float_as_uint(a); ua += 0x7fffu + ((ua >> 16) & 1u);  // RNE
  unsigned ub = __float_as_uint(b); ub += 0x7fffu + ((ub >> 16) & 1u);
  return (ua >> 16) | (ub & 0xffff0000u);
}

// ---- kernel 1: mask (fp64-exact; verified green) + write mask-zeroed bf16
//      copy of x into ws. grid (8 rb, 8 kgrp), 256 thr. UNCHANGED.
__global__ __launch_bounds__(256) void mask_convert_kernel(
    const float* __restrict__ x, unsigned* __restrict__ xbf) {
  const int rb = blockIdx.x;
  const int g  = blockIdx.y;
  const int t  = threadIdx.x;
  __shared__ double part[256];
  __shared__ unsigned sh_bits;

  const float* base = x + (size_t)rb * 16 * KDIM + g * 512 + t * 2;
  double s = 0.0;
#pragma unroll
  for (int r = 0; r < 16; ++r) {
    float2v a = *(const float2v*)(base + (size_t)r * KDIM);
    s += (double)fabsf(a[0]) + (double)fabsf(a[1]);
  }
  part[t] = s;
  __syncthreads();
  if (t < 8) {                        // t = kb-local (8 kbs per 512-col group)
    double acc = 0.0;
#pragma unroll
    for (int u = 0; u < 32; ++u) acc += part[t * 32 + u];
    bool on = (acc * (1.0 / 1024.0)) > (double)0.8f;
    unsigned long long bal = __ballot(on);
    if (t == 0) sh_bits = (unsigned)(bal & 0xffu);
  }
  __syncthreads();
  const unsigned keep = (sh_bits >> (t >> 5)) & 1u;

  unsigned* dst = xbf + (size_t)rb * 16 * (KDIM / 2) + g * 256 + t;
#pragma unroll
  for (int r = 0; r < 16; ++r) {      // reload (L1-hot) + pack/zero + store
    float2v a = *(const float2v*)(base + (size_t)r * KDIM);
    dst[(size_t)r * (KDIM / 2)] = keep ? pk_bf16(a[0], a[1]) : 0u;
  }
}

// ---- kernel 1b: out[r][n] = bias[n] so gemm ksegs can atomically accumulate
// order-free. grid (43, 128): 11008 = 43*256 cols, 128 rows.
__global__ __launch_bounds__(256) void bias_init_kernel(
    const float* __restrict__ bias, float* __restrict__ out) {
  const int n = blockIdx.x * 256 + threadIdx.x;
  out[(size_t)blockIdx.y * NCOL + n] = bias[n];
}

// ---- kernel 2: dense GEMM on masked bf16 x. grid (344, KSEG=4), 256 thr.
// M=128 x N=32 per block, 16 kbs per block. W staging via
// __builtin_amdgcn_global_load_lds width=16 (m97-proven): no dest regs ->
// the compiler cannot sink the load to its consumer (R1-R3 post-mortem:
// register-destination prefetches were sunk, VGPR_Count 56 proved no live
// pipeline existed, every phase paid full serial latency). W is fp32 in
// LDS, linear [64][128B] per gl_lds lane-order rule; fp32->bf16 at
// fragment build. K-split x4 for TLP. Atomics accumulate ksegs.
// R5 de-risk vs R4 (2x container failure, cause unknown): stage() is
// straight-line macro code (no lambda around the builtin); launch-bounds
// occupancy pin dropped.
__global__ __launch_bounds__(256) void gemm_kernel(
    const unsigned* __restrict__ xbf, const float* __restrict__ w,
    float* __restrict__ out) {

  __shared__ __align__(16) uint8_t lds[2 * TILE_B];

  const int tid  = threadIdx.x;
  const int lane = tid & 63;
  const int wv   = tid >> 6;
  const int c    = lane & 15;
  const int q    = lane >> 4;
  const int n0   = blockIdx.x * 32;
  const int kb0  = blockIdx.y * KB_PER_SEG;

  f32x4 acc[2][2] = {};               // [band][even/odd]

  // W staging geometry: thread t covers, for round r in {0,1}:
  //   LDS byte L = r*4096 + wv*1024 + lane*16  ->  row k = r*32 + (t>>3),
  //   byte-in-row (t&7)*16; global: W[kb*64 + k][n0 + (t&7)*4 ..+3]
  const int kA = tid >> 3;            // 0..31
  const int cB = (tid & 7) * 4;       // float col offset in tile row
  const float* gW = w + (size_t)kA * NCOL + n0 + cB;

#define STAGE(PBUF, KBI)                                                     \
  {                                                                          \
    const float* g_ = gW + (size_t)(KBI) * 64 * NCOL;                        \
    __builtin_amdgcn_global_load_lds(                                        \
        (const AS1 void*)g_,                                                 \
        (AS3 void*)(lds + (PBUF) * TILE_B + wv * 1024), 16, 0, 0);           \
    __builtin_amdgcn_global_load_lds(                                        \
        (const AS1 void*)(g_ + (size_t)32 * NCOL),                           \
        (AS3 void*)(lds + (PBUF) * TILE_B + 4096 + wv * 1024), 16, 0, 0);    \
  }

  // A source (bf16 masked x, L2-resident): uint4v idx = row*512 + kb*8 + ks*4 + q
  const uint4v* aB0 = (const uint4v*)xbf + (size_t)((wv * 2 + 0) * 16 + c) * (KDIM / 8) + q;
  const uint4v* aB1 = (const uint4v*)xbf + (size_t)((wv * 2 + 1) * 16 + c) * (KDIM / 8) + q;

  auto compute = [&](const uint8_t* buf, int kbi) {
    union { uint4v u; short8 v; } a00, a01, a10, a11;
    a00.u = aB0[kbi * 8 + 0];        // band0 ks=0
    a01.u = aB0[kbi * 8 + 4];        // band0 ks=1
    a10.u = aB1[kbi * 8 + 0];        // band1 ks=0
    a11.u = aB1[kbi * 8 + 4];        // band1 ks=1

#pragma unroll
    for (int ks = 0; ks < 2; ++ks) {
      // rows k = ks*32 + q*8 + j hold cols (2c, 2c+1) as float2 at byte k*128 + c*8
      const uint8_t* wb = buf + (size_t)(ks * 32 + q * 8) * 128 + c * 8;
      float2v r[8];
#pragma unroll
      for (int j = 0; j < 8; ++j)
        r[j] = *(const float2v*)(wb + (size_t)j * 128);
      union { short8 v; unsigned u[4]; } be, bo;
#pragma unroll
      for (int p = 0; p < 4; ++p) {
        be.u[p] = pk_bf16(r[2 * p][0], r[2 * p + 1][0]);   // even col 2c
        bo.u[p] = pk_bf16(r[2 * p][1], r[2 * p + 1][1]);   // odd  col 2c+1
      }
      const short8 a0 = ks ? a01.v : a00.v;
      const short8 a1 = ks ? a11.v : a10.v;
      acc[0][0] = __builtin_amdgcn_mfma_f32_16x16x32_bf16(a0, be.v, acc[0][0], 0, 0, 0);
      acc[0][1] = __builtin_amdgcn_mfma_f32_16x16x32_bf16(a0, bo.v, acc[0][1], 0, 0, 0);
      acc[1][0] = __builtin_amdgcn_mfma_f32_16x16x32_bf16(a1, be.v, acc[1][0], 0, 0, 0);
      acc[1][1] = __builtin_amdgcn_mfma_f32_16x16x32_bf16(a1, bo.v, acc[1][1], 0, 0, 0);
    }
  };

  // prologue: stage first tile, drain
  STAGE(0, kb0);
  __syncthreads();

  int p = 0;
  for (int i = 0; i < KB_PER_SEG; ++i) {
    if (i + 1 < KB_PER_SEG) STAGE(p ^ 1, kb0 + i + 1);  // in flight during compute
    compute(lds + p * TILE_B, kb0 + i);
    __syncthreads();               // drains stage(i+1); guards buf reuse
    p ^= 1;
  }
#undef STAGE

  // epilogue: D row = band*16 + q*4 + pp, cols (2c,2c+1); native fp32
  // atomic add (relaxed, agent scope). 4 ksegs per address, lane-disjoint.
  const int colE = n0 + 2 * c;
#pragma unroll
  for (int b = 0; b < 2; ++b) {
#pragma unroll
    for (int pp = 0; pp < 4; ++pp) {
      const int row = (wv * 2 + b) * 16 + q * 4 + pp;
      float* pdst = out + (size_t)row * NCOL + colE;
      __hip_atomic_fetch_add(pdst,     acc[b][0][pp], __ATOMIC_RELAXED,
                             __HIP_MEMORY_SCOPE_AGENT);
      __hip_atomic_fetch_add(pdst + 1, acc[b][1][pp], __ATOMIC_RELAXED,
                             __HIP_MEMORY_SCOPE_AGENT);
    }
  }
}

extern "C" void kernel_launch(void* const* d_in, const int* in_sizes, int n_in,
                              void* d_out, int out_size, void* d_ws, size_t ws_size,
                              hipStream_t stream) {
  const float* x    = (const float*)d_in[0];
  const float* w    = (const float*)d_in[1];
  const float* bias = (const float*)d_in[2];
  float* out        = (float*)d_out;
  unsigned* xbf     = (unsigned*)d_ws;    // 128 x 4096 bf16 (1 MiB)

  hipLaunchKernelGGL(mask_convert_kernel, dim3(8, 8), dim3(256), 0, stream, x, xbf);
  hipLaunchKernelGGL(bias_init_kernel, dim3(43, 128), dim3(256), 0, stream, bias, out);
  hipLaunchKernelGGL(gemm_kernel, dim3(344, KSEG), dim3(256), 0, stream,
                     xbf, w, out);
}